// Round 8
// baseline (139.059 us; speedup 1.0000x reference)
//
#include <hip/hip_runtime.h>
#include <hip/hip_bf16.h>

// MobileMQA reduction (softmax over size-1 axis == 1; Q/K dead):
//   Wvt[d][c] = mean_h W_qkv[c][1024+h*64+d] (bf16), bv[d] likewise (f32)
//   V[b,n,d]  = sum_c x[b,c,n]*Wvt[d][c] + bv[d]     (gemm1, MFMA bf16, V stored bf16)
//   Z[b] = V[b] viewed (128,512); P[b] = Z[b]@Wproj + bproj   (gemm2, MFMA bf16)
//   out[b,c',i] = P[b, i&127, c']  fp32                (8x replication in gemm2 epilogue)
//
// R8 = R7 + B-operand-in-registers: each wave's 16 B-columns over full K=512
// are 16 short8 frags (64 VGPR), loaded once from L2 at kernel start.
// Inner loops stage ONLY the A stream through 8KB double-buffered LDS with a
// single barrier per K-chunk. K-loop fully unrolled for static frag indexing.

typedef unsigned int u32;
typedef __attribute__((ext_vector_type(8))) short short8;  // 8 bf16 = 4 VGPR
typedef __attribute__((ext_vector_type(4))) float f32x4;

__device__ __forceinline__ void gll16(const void* g, void* l) {
  __builtin_amdgcn_global_load_lds(
      (const __attribute__((address_space(1))) u32*)g,
      (__attribute__((address_space(3))) u32*)l, 16, 0, 0);
}
__device__ __forceinline__ u32 packbf2(float a, float b) {
  __hip_bfloat162 p = __float22bfloat162_rn(make_float2(a, b));
  return *(u32*)&p;
}

// blocks 0..255: Wproj 32x32 tile transpose -> Wpt bf16. blocks 256..383: Wvt + bv.
__global__ __launch_bounds__(256) void prep_kernel(
    const float* __restrict__ Wqkv, const float* __restrict__ bqkv,
    const float* __restrict__ Wproj, __hip_bfloat16* __restrict__ Wvt,
    float* __restrict__ bv, __hip_bfloat16* __restrict__ Wpt) {
  const int bid = blockIdx.x, t = (int)threadIdx.x;
  if (bid < 256) {
    __shared__ float Tl[32][33];
    const int tr = bid >> 4, tc = bid & 15;
    const int c0 = tr * 32, p0 = tc * 32;
    const int r = t >> 5, col = t & 31;
#pragma unroll
    for (int a = 0; a < 4; ++a)
      Tl[r + a * 8][col] = Wproj[(size_t)(c0 + r + a * 8) * 512 + p0 + col];
    __syncthreads();
#pragma unroll
    for (int a = 0; a < 4; ++a)
      Wpt[(size_t)(p0 + r + a * 8) * 512 + c0 + col] = __float2bfloat16(Tl[col][r + a * 8]);
  } else {
    const int g = (bid - 256) * 256 + t;  // 0..32767
    const int c = g >> 6, d = g & 63;
    float s = 0.f;
#pragma unroll
    for (int h = 0; h < 8; ++h) s += Wqkv[(size_t)c * 1536 + 1024 + h * 64 + d];
    Wvt[(size_t)d * 512 + c] = __float2bfloat16(s * 0.125f);
    if (g < 64) {
      float sb = 0.f;
#pragma unroll
      for (int h = 0; h < 8; ++h) sb += bqkv[1024 + h * 64 + d];
      bv[d] = sb * 0.125f;
    }
  }
}

// gemm1: grid (32 nt, 32 b), 256 thr = 4 waves; wave w owns d in [w*16, w*16+16).
// Block tile 32n x 64d, BK=64, 8 chunks fully unrolled, 1 barrier/chunk.
// B (Wvt) entirely in registers: br[8][2] short8 per thread. A (x) staged:
// float4 global loads -> bf16 pack -> XOR-swizzled LDS -> ds_read_b128 frags.
__global__ __launch_bounds__(256) void gemm1_kernel(
    const float* __restrict__ x, const __hip_bfloat16* __restrict__ Wvt,
    const float* __restrict__ bv, __hip_bfloat16* __restrict__ V) {
  __shared__ char Xl[2][4096];  // [n<32][c<64] bf16, byte ^= ((n&7)<<4)
  const int nt = blockIdx.x, b = blockIdx.y;
  const int t = (int)threadIdx.x, w = t >> 6, lane = t & 63;
  const int lr = lane & 15, ko = lane >> 4;

  // B-frags for the whole K range (L2-hot 64KB Wvt): 16 dwordx4 loads.
  const __hip_bfloat16* wg = Wvt + (size_t)(w * 16 + lr) * 512 + ko * 8;
  short8 br[8][2];
#pragma unroll
  for (int kc = 0; kc < 8; ++kc)
#pragma unroll
    for (int kb = 0; kb < 2; ++kb)
      br[kc][kb] = *(const short8*)(wg + kc * 64 + kb * 32);

  const int cq = t >> 3, nq = t & 7;  // staging: c-pair base cq*2, n-quad nq
  const float* xg = x + (size_t)b * 524288 + (size_t)(cq * 2) * 1024 + nt * 32 + nq * 4;

  float4 xr0, xr1;
  f32x4 acc[2] = {{0.f, 0.f, 0.f, 0.f}, {0.f, 0.f, 0.f, 0.f}};

#define XLOAD(kc)                                                         \
  do {                                                                    \
    xr0 = *(const float4*)(xg + (size_t)(kc) * 65536);                    \
    xr1 = *(const float4*)(xg + (size_t)(kc) * 65536 + 1024);             \
  } while (0)
#define XWRITE(buf)                                                       \
  do {                                                                    \
    _Pragma("unroll") for (int j = 0; j < 4; ++j) {                       \
      int n = nq * 4 + j;                                                 \
      u32 pv = packbf2(((const float*)&xr0)[j], ((const float*)&xr1)[j]); \
      *(u32*)(&Xl[buf][0] + ((n * 128 + cq * 4) ^ ((n & 7) << 4))) = pv;  \
    }                                                                     \
  } while (0)

  XLOAD(0);
  XWRITE(0);
  __syncthreads();
#pragma unroll
  for (int kc = 0; kc < 8; ++kc) {
    const int cur = kc & 1;
    if (kc < 7) XLOAD(kc + 1);
    const char* Xb = &Xl[cur][0];
#pragma unroll
    for (int kb = 0; kb < 2; ++kb) {
      short8 af[2];
#pragma unroll
      for (int mi = 0; mi < 2; ++mi) {
        int n = mi * 16 + lr;
        af[mi] = *(const short8*)(Xb + ((n * 128 + kb * 64 + ko * 16) ^ ((n & 7) << 4)));
      }
#pragma unroll
      for (int mi = 0; mi < 2; ++mi)
        acc[mi] = __builtin_amdgcn_mfma_f32_16x16x32_bf16(af[mi], br[kc][kb], acc[mi], 0, 0, 0);
    }
    if (kc < 7) XWRITE(cur ^ 1);
    __syncthreads();
  }
#undef XLOAD
#undef XWRITE

  // D: col (lane&15) = d-local, row = ko*4 + r = n-local. +bv, bf16 store.
  const int d = w * 16 + lr;
  const float bvd = bv[d];
#pragma unroll
  for (int mi = 0; mi < 2; ++mi) {
    const int n0 = nt * 32 + mi * 16 + ko * 4;
#pragma unroll
    for (int r = 0; r < 4; ++r)
      V[((size_t)b * 1024 + n0 + r) * 64 + d] = __float2bfloat16(acc[mi][r] + bvd);
  }
}

// gemm2: 1024 blocks (XCD-chunked bijective), 256 thr; wave w owns c' quarter.
// Block tile 32j x 64c', BK=64, 8 chunks unrolled, 1 barrier/chunk.
// B (Wpt rows ct*64..+64) in registers; A (Z) via pre-swizzled global_load_lds.
// Epilogue: P -> stride-65 LDS -> 8x-replicated fully-coalesced float4 stores.
__global__ __launch_bounds__(256) void gemm2_kernel(
    const __hip_bfloat16* __restrict__ Vb, const __hip_bfloat16* __restrict__ Wpt,
    const float* __restrict__ bproj, float* __restrict__ out) {
  __shared__ char smem[8448];  // Zl[2][4096]; Pl (32*65*4 = 8320B) aliases base
  const int bid = (int)blockIdx.x;
  const int lin = ((bid & 7) << 7) | (bid >> 3);  // XCD chunking (1024 % 8 == 0)
  const int ct = lin & 7, jt = (lin >> 3) & 3, b = lin >> 5;
  const int t = (int)threadIdx.x, w = t >> 6, lane = t & 63;
  const int lr = lane & 15, ko = lane >> 4;

  // B-frags: Wpt[p = ct*64 + w*16 + lr][k], full K=512 -> 16 dwordx4 (L2-hot).
  const __hip_bfloat16* wg = Wpt + (size_t)(ct * 64 + w * 16 + lr) * 512 + ko * 8;
  short8 br[8][2];
#pragma unroll
  for (int kc = 0; kc < 8; ++kc)
#pragma unroll
    for (int kb = 0; kb < 2; ++kb)
      br[kc][kb] = *(const short8*)(wg + kc * 64 + kb * 32);

  const __hip_bfloat16* Zg = Vb + (size_t)b * 65536 + (size_t)(jt * 32) * 512;
  const int sr = t >> 3, sw = t & 7;  // stage: row, granule

#define STAGE(buf, kc)                                                    \
  gll16(Zg + (size_t)sr * 512 + (kc) * 64 + ((sw ^ (sr & 7)) << 3),       \
        &smem[0] + (buf) * 4096 + t * 16)

  f32x4 acc[2] = {{0.f, 0.f, 0.f, 0.f}, {0.f, 0.f, 0.f, 0.f}};
  STAGE(0, 0);
  __syncthreads();
#pragma unroll
  for (int kc = 0; kc < 8; ++kc) {
    const int cur = kc & 1;
    if (kc < 7) STAGE(cur ^ 1, kc + 1);
    const char* Zb = &smem[0] + cur * 4096;
#pragma unroll
    for (int kb = 0; kb < 2; ++kb) {
      short8 af[2];
#pragma unroll
      for (int mi = 0; mi < 2; ++mi) {
        int j = mi * 16 + lr;
        af[mi] = *(const short8*)(Zb + j * 128 + (((kb * 4 + ko) ^ (j & 7)) << 4));
      }
#pragma unroll
      for (int mi = 0; mi < 2; ++mi)
        acc[mi] = __builtin_amdgcn_mfma_f32_16x16x32_bf16(af[mi], br[kc][kb], acc[mi], 0, 0, 0);
    }
    __syncthreads();
  }
#undef STAGE

  // P tile (+bproj) -> LDS [32][65] f32 (aliases Zl; safe after final barrier)
  float* Pl = (float*)&smem[0];
  const int p = w * 16 + lr;
  const float bp = bproj[ct * 64 + p];
#pragma unroll
  for (int mi = 0; mi < 2; ++mi) {
#pragma unroll
    for (int r = 0; r < 4; ++r)
      Pl[(mi * 16 + ko * 4 + r) * 65 + p] = acc[mi][r] + bp;
  }
  __syncthreads();
  // out[b][ct*64+cl][rep*128 + jt*32 + j]; 4096 float4 per block, coalesced
  float* ob = out + ((size_t)b * 512 + ct * 64) * 1024 + jt * 32;
#pragma unroll
  for (int k = 0; k < 16; ++k) {
    int F = t + 256 * k;
    int cl = F >> 6;         // 0..63
    int rem = F & 63;
    int rep = rem >> 3;      // 0..7
    int j4 = (rem & 7) * 4;  // 0..28
    float4 v;
    v.x = Pl[(j4 + 0) * 65 + cl];
    v.y = Pl[(j4 + 1) * 65 + cl];
    v.z = Pl[(j4 + 2) * 65 + cl];
    v.w = Pl[(j4 + 3) * 65 + cl];
    *(float4*)(ob + (size_t)cl * 1024 + rep * 128 + j4) = v;
  }
}

extern "C" void kernel_launch(void* const* d_in, const int* in_sizes, int n_in,
                              void* d_out, int out_size, void* d_ws, size_t ws_size,
                              hipStream_t stream) {
  (void)in_sizes; (void)n_in; (void)out_size; (void)ws_size;
  const float* x     = (const float*)d_in[0];
  const float* Wqkv  = (const float*)d_in[1];
  const float* bqkv  = (const float*)d_in[2];
  const float* Wproj = (const float*)d_in[3];
  const float* bproj = (const float*)d_in[4];
  float* out = (float*)d_out;
  char* ws = (char*)d_ws;
  __hip_bfloat16* Wvt = (__hip_bfloat16*)(ws);            // 64*512*2   = 65536 B
  __hip_bfloat16* Wpt = (__hip_bfloat16*)(ws + 65536);    // 512*512*2  = 524288 B
  float*          bv  = (float*)(ws + 589824);            // 256 B
  __hip_bfloat16* Vb  = (__hip_bfloat16*)(ws + 590080);   // 32*1024*64*2 = 4 MiB

  prep_kernel<<<384, 256, 0, stream>>>(Wqkv, bqkv, Wproj, Wvt, bv, Wpt);
  gemm1_kernel<<<dim3(32, 32), 256, 0, stream>>>(x, Wvt, bv, Vb);
  gemm2_kernel<<<1024, 256, 0, stream>>>(Vb, Wpt, bproj, out);
}

// Round 9
// 137.064 us; speedup vs baseline: 1.0146x; 1.0146x over previous
//
#include <hip/hip_runtime.h>
#include <hip/hip_bf16.h>

// MobileMQA reduction (softmax over size-1 axis == 1; Q/K dead):
//   Wvt[d][c] = mean_h W_qkv[c][1024+h*64+d] (bf16), bv[d] likewise (f32)
//   V[b,n,d]  = sum_c x[b,c,n]*Wvt[d][c] + bv[d]     (gemm1, MFMA bf16, V stored bf16)
//   Z[b] = V[b] viewed (128,512); P[b] = Z[b]@Wproj + bproj   (gemm2, MFMA bf16)
//   out[b,c',i] = P[b, i&127, c']  fp32                (8x replication in gemm2 epilogue)
//
// R9: vmcnt-free barriers + depth-2 register prefetch.
//  - NO global_load_lds (it forces s_waitcnt vmcnt(0) before every s_barrier).
//  - A-stream reg-staged with 2 rotating reg sets issued 2 chunks ahead;
//    compiler emits counted vmcnt before the ds_write (register dep), and
//    __syncthreads drains only lgkmcnt. Fully-unrolled K-loop -> static regs.
//  - B operands in registers (L2-hot), 8KB LDS/block.

typedef unsigned int u32;
typedef __attribute__((ext_vector_type(8))) short short8;  // 8 bf16 = 4 VGPR
typedef __attribute__((ext_vector_type(4))) float f32x4;

__device__ __forceinline__ u32 packbf2(float a, float b) {
  __hip_bfloat162 p = __float22bfloat162_rn(make_float2(a, b));
  return *(u32*)&p;
}

// blocks 0..255: Wproj 32x32 tile transpose -> Wpt bf16. blocks 256..383: Wvt + bv.
__global__ __launch_bounds__(256) void prep_kernel(
    const float* __restrict__ Wqkv, const float* __restrict__ bqkv,
    const float* __restrict__ Wproj, __hip_bfloat16* __restrict__ Wvt,
    float* __restrict__ bv, __hip_bfloat16* __restrict__ Wpt) {
  const int bid = blockIdx.x, t = (int)threadIdx.x;
  if (bid < 256) {
    __shared__ float Tl[32][33];
    const int tr = bid >> 4, tc = bid & 15;
    const int c0 = tr * 32, p0 = tc * 32;
    const int r = t >> 5, col = t & 31;
#pragma unroll
    for (int a = 0; a < 4; ++a)
      Tl[r + a * 8][col] = Wproj[(size_t)(c0 + r + a * 8) * 512 + p0 + col];
    __syncthreads();
#pragma unroll
    for (int a = 0; a < 4; ++a)
      Wpt[(size_t)(p0 + r + a * 8) * 512 + c0 + col] = __float2bfloat16(Tl[col][r + a * 8]);
  } else {
    const int g = (bid - 256) * 256 + t;  // 0..32767
    const int c = g >> 6, d = g & 63;
    float s = 0.f;
#pragma unroll
    for (int h = 0; h < 8; ++h) s += Wqkv[(size_t)c * 1536 + 1024 + h * 64 + d];
    Wvt[(size_t)d * 512 + c] = __float2bfloat16(s * 0.125f);
    if (g < 64) {
      float sb = 0.f;
#pragma unroll
      for (int h = 0; h < 8; ++h) sb += bqkv[1024 + h * 64 + d];
      bv[d] = sb * 0.125f;
    }
  }
}

// gemm1: grid (32 nt, 32 b), 256 thr = 4 waves; wave w owns d in [w*16, w*16+16).
// Block tile 32n x 64d, BK=64, 8 chunks fully unrolled, 1 lgkm-only barrier/chunk.
// B (Wvt) in registers. A (x): depth-2 reg prefetch -> bf16 pack -> swizzled LDS.
__global__ __launch_bounds__(256) void gemm1_kernel(
    const float* __restrict__ x, const __hip_bfloat16* __restrict__ Wvt,
    const float* __restrict__ bv, __hip_bfloat16* __restrict__ V) {
  __shared__ char Xl[2][4096];  // [n<32][c<64] bf16, byte ^= ((n&7)<<4)
  const int nt = blockIdx.x, b = blockIdx.y;
  const int t = (int)threadIdx.x, w = t >> 6, lane = t & 63;
  const int lr = lane & 15, ko = lane >> 4;

  // B-frags for full K (L2-hot 64KB Wvt): 16 dwordx4 loads.
  const __hip_bfloat16* wg = Wvt + (size_t)(w * 16 + lr) * 512 + ko * 8;
  short8 br[8][2];
#pragma unroll
  for (int kc = 0; kc < 8; ++kc)
#pragma unroll
    for (int kb = 0; kb < 2; ++kb)
      br[kc][kb] = *(const short8*)(wg + kc * 64 + kb * 32);

  const int cq = t >> 3, nq = t & 7;  // staging: c-pair base cq*2, n-quad nq
  const float* xg = x + (size_t)b * 524288 + (size_t)(cq * 2) * 1024 + nt * 32 + nq * 4;

  float4 xa0, xa1, xb0, xb1;  // two rotating prefetch sets
  f32x4 acc[2] = {{0.f, 0.f, 0.f, 0.f}, {0.f, 0.f, 0.f, 0.f}};

#define XLOAD(r0, r1, kc)                                                 \
  do {                                                                    \
    r0 = *(const float4*)(xg + (size_t)(kc) * 65536);                     \
    r1 = *(const float4*)(xg + (size_t)(kc) * 65536 + 1024);              \
  } while (0)
#define XWRITE(r0, r1, buf)                                               \
  do {                                                                    \
    _Pragma("unroll") for (int j = 0; j < 4; ++j) {                       \
      int n = nq * 4 + j;                                                 \
      u32 pv = packbf2(((const float*)&r0)[j], ((const float*)&r1)[j]);   \
      *(u32*)(&Xl[buf][0] + ((n * 128 + cq * 4) ^ ((n & 7) << 4))) = pv;  \
    }                                                                     \
  } while (0)

  XLOAD(xa0, xa1, 0);
  XLOAD(xb0, xb1, 1);
  XWRITE(xa0, xa1, 0);
  __syncthreads();
#pragma unroll
  for (int kc = 0; kc < 8; ++kc) {
    const int cur = kc & 1;
    if (kc < 6) {
      if (cur == 0) XLOAD(xa0, xa1, kc + 2);  // xa consumed by prior XWRITE
      else          XLOAD(xb0, xb1, kc + 2);
    }
    const char* Xb = &Xl[cur][0];
#pragma unroll
    for (int kb = 0; kb < 2; ++kb) {
      short8 af[2];
#pragma unroll
      for (int mi = 0; mi < 2; ++mi) {
        int n = mi * 16 + lr;
        af[mi] = *(const short8*)(Xb + ((n * 128 + kb * 64 + ko * 16) ^ ((n & 7) << 4)));
      }
#pragma unroll
      for (int mi = 0; mi < 2; ++mi)
        acc[mi] = __builtin_amdgcn_mfma_f32_16x16x32_bf16(af[mi], br[kc][kb], acc[mi], 0, 0, 0);
    }
    if (kc < 7) {
      if (cur == 0) XWRITE(xb0, xb1, 1);  // chunk kc+1 lives in xb when kc even
      else          XWRITE(xa0, xa1, 0);
    }
    __syncthreads();
  }
#undef XLOAD
#undef XWRITE

  // D: col (lane&15) = d-local, row = ko*4 + r = n-local. +bv, bf16 store.
  const int d = w * 16 + lr;
  const float bvd = bv[d];
#pragma unroll
  for (int mi = 0; mi < 2; ++mi) {
    const int n0 = nt * 32 + mi * 16 + ko * 4;
#pragma unroll
    for (int r = 0; r < 4; ++r)
      V[((size_t)b * 1024 + n0 + r) * 64 + d] = __float2bfloat16(acc[mi][r] + bvd);
  }
}

// gemm2: 1024 blocks (XCD-chunked bijective), 256 thr; wave w owns c' quarter.
// Block tile 32j x 64c', BK=64, 8 chunks unrolled, lgkm-only barriers.
// B (Wpt) in registers; A (Z): depth-2 reg prefetch -> swizzled ds_write_b128.
// Epilogue: P -> stride-65 LDS -> 8x-replicated fully-coalesced float4 stores.
__global__ __launch_bounds__(256) void gemm2_kernel(
    const __hip_bfloat16* __restrict__ Vb, const __hip_bfloat16* __restrict__ Wpt,
    const float* __restrict__ bproj, float* __restrict__ out) {
  __shared__ char smem[8448];  // Zl[2][4096]; Pl (32*65*4 = 8320B) aliases base
  const int bid = (int)blockIdx.x;
  const int lin = ((bid & 7) << 7) | (bid >> 3);  // XCD chunking (1024 % 8 == 0)
  const int ct = lin & 7, jt = (lin >> 3) & 3, b = lin >> 5;
  const int t = (int)threadIdx.x, w = t >> 6, lane = t & 63;
  const int lr = lane & 15, ko = lane >> 4;

  // B-frags: Wpt[p = ct*64 + w*16 + lr][k], full K=512 -> 16 dwordx4 (L2-hot).
  const __hip_bfloat16* wg = Wpt + (size_t)(ct * 64 + w * 16 + lr) * 512 + ko * 8;
  short8 br[8][2];
#pragma unroll
  for (int kc = 0; kc < 8; ++kc)
#pragma unroll
    for (int kb = 0; kb < 2; ++kb)
      br[kc][kb] = *(const short8*)(wg + kc * 64 + kb * 32);

  const __hip_bfloat16* Zg = Vb + (size_t)b * 65536 + (size_t)(jt * 32) * 512;
  const int sr = t >> 3, sw = t & 7;  // stage: row, granule
  short8 za, zb;  // two rotating prefetch sets

#define ZLOAD(zr, kc) zr = *(const short8*)(Zg + (size_t)sr * 512 + (kc) * 64 + sw * 8)
#define ZWRITE(zr, buf) \
  *(short8*)(&smem[0] + (buf) * 4096 + sr * 128 + (((sw) ^ (sr & 7)) << 4)) = zr

  f32x4 acc[2] = {{0.f, 0.f, 0.f, 0.f}, {0.f, 0.f, 0.f, 0.f}};
  ZLOAD(za, 0);
  ZLOAD(zb, 1);
  ZWRITE(za, 0);
  __syncthreads();
#pragma unroll
  for (int kc = 0; kc < 8; ++kc) {
    const int cur = kc & 1;
    if (kc < 6) {
      if (cur == 0) ZLOAD(za, kc + 2);
      else          ZLOAD(zb, kc + 2);
    }
    const char* Zb = &smem[0] + cur * 4096;
#pragma unroll
    for (int kb = 0; kb < 2; ++kb) {
      short8 af[2];
#pragma unroll
      for (int mi = 0; mi < 2; ++mi) {
        int j = mi * 16 + lr;
        af[mi] = *(const short8*)(Zb + j * 128 + (((kb * 4 + ko) ^ (j & 7)) << 4));
      }
#pragma unroll
      for (int mi = 0; mi < 2; ++mi)
        acc[mi] = __builtin_amdgcn_mfma_f32_16x16x32_bf16(af[mi], br[kc][kb], acc[mi], 0, 0, 0);
    }
    if (kc < 7) {
      if (cur == 0) ZWRITE(zb, 1);
      else          ZWRITE(za, 0);
    }
    __syncthreads();
  }
#undef ZLOAD
#undef ZWRITE

  // P tile (+bproj) -> LDS [32][65] f32 (aliases Zl; safe after final barrier)
  float* Pl = (float*)&smem[0];
  const int p = w * 16 + lr;
  const float bp = bproj[ct * 64 + p];
#pragma unroll
  for (int mi = 0; mi < 2; ++mi) {
#pragma unroll
    for (int r = 0; r < 4; ++r)
      Pl[(mi * 16 + ko * 4 + r) * 65 + p] = acc[mi][r] + bp;
  }
  __syncthreads();
  // out[b][ct*64+cl][rep*128 + jt*32 + j]; 4096 float4 per block, coalesced
  float* ob = out + ((size_t)b * 512 + ct * 64) * 1024 + jt * 32;
#pragma unroll
  for (int k = 0; k < 16; ++k) {
    int F = t + 256 * k;
    int cl = F >> 6;         // 0..63
    int rem = F & 63;
    int rep = rem >> 3;      // 0..7
    int j4 = (rem & 7) * 4;  // 0..28
    float4 v;
    v.x = Pl[(j4 + 0) * 65 + cl];
    v.y = Pl[(j4 + 1) * 65 + cl];
    v.z = Pl[(j4 + 2) * 65 + cl];
    v.w = Pl[(j4 + 3) * 65 + cl];
    *(float4*)(ob + (size_t)cl * 1024 + rep * 128 + j4) = v;
  }
}

extern "C" void kernel_launch(void* const* d_in, const int* in_sizes, int n_in,
                              void* d_out, int out_size, void* d_ws, size_t ws_size,
                              hipStream_t stream) {
  (void)in_sizes; (void)n_in; (void)out_size; (void)ws_size;
  const float* x     = (const float*)d_in[0];
  const float* Wqkv  = (const float*)d_in[1];
  const float* bqkv  = (const float*)d_in[2];
  const float* Wproj = (const float*)d_in[3];
  const float* bproj = (const float*)d_in[4];
  float* out = (float*)d_out;
  char* ws = (char*)d_ws;
  __hip_bfloat16* Wvt = (__hip_bfloat16*)(ws);            // 64*512*2   = 65536 B
  __hip_bfloat16* Wpt = (__hip_bfloat16*)(ws + 65536);    // 512*512*2  = 524288 B
  float*          bv  = (float*)(ws + 589824);            // 256 B
  __hip_bfloat16* Vb  = (__hip_bfloat16*)(ws + 590080);   // 32*1024*64*2 = 4 MiB

  prep_kernel<<<384, 256, 0, stream>>>(Wqkv, bqkv, Wproj, Wvt, bv, Wpt);
  gemm1_kernel<<<dim3(32, 32), 256, 0, stream>>>(x, Wvt, bv, Vb);
  gemm2_kernel<<<1024, 256, 0, stream>>>(Vb, Wpt, bproj, out);
}